// Round 17
// baseline (379.467 us; speedup 1.0000x reference)
//
#include <hip/hip_runtime.h>
#include <hip/hip_bf16.h>
#include <hip/hip_cooperative_groups.h>
#include <math.h>

namespace cg = cooperative_groups;

#define NN 200000
#define NE 6400000

#define BNODES 782                     // nodes per bucket (NB = 256 = #CUs)
#define NB 256
#define CAP 27648                      // 27*1024; mean 25000 -> +16 sigma
#define SCT 1024                       // threads per block (16 waves)
#define CHUNK (NE / NB)                // 25000; 25 iters/thread

// ---- workspace layout (4-byte words) ----
#define W_DACC 0                       // double (2 words)
#define W_UV   4                       // 8 floats
#define W_CUR  16                      // NB uints
#define W_NOFF 1024                    // NN uints
#define W_NCNT (W_NOFF + NN)           // NN uints
#define W_META (W_NCNT + NN)           // NB*CAP u32: sn(18b) | dl(10b)<<18 (unsorted)
#define W_RANK (W_META + NB*CAP)       // NB*CAP u16 ranks
#define W_META2 (W_RANK + (NB*CAP + 1) / 2)   // NB*CAP u32 (sorted)
#define W_Z2   (W_META2 + NB*CAP)      // 2*NN f32
#define W_TOTAL (W_Z2 + 2*NN)          // ~18.5M words = 74 MB

__launch_bounds__(SCT)
__global__ void k_fused(const int* __restrict__ src, const int* __restrict__ dst,
                        const float2* __restrict__ h, const float* __restrict__ fc1,
                        const float* __restrict__ attn1, const float* __restrict__ fc2,
                        const float* __restrict__ attn2, const float* __restrict__ mlp_w,
                        const float* __restrict__ mlp_b, float* __restrict__ out,
                        unsigned* __restrict__ ws) {
    cg::grid_group grid = cg::this_grid();
    double*   dacc    = (double*)ws;
    float*    uv      = (float*)(ws + W_UV);
    unsigned* cur     = ws + W_CUR;
    unsigned* nodeoff = ws + W_NOFF;
    unsigned* nodecnt = ws + W_NCNT;
    unsigned* meta    = ws + W_META;
    unsigned short* rank16 = (unsigned short*)(ws + W_RANK);
    unsigned* meta2   = ws + W_META2;
    float2*   z2      = (float2*)(ws + W_Z2);

    __shared__ unsigned shA[BNODES];   // scatter cnt / sort hist
    __shared__ unsigned shB[BNODES];   // scatter gbase / sort base
    __shared__ unsigned shC[BNODES];   // sort scan
    __shared__ double sm[16];

    const int b = blockIdx.x, t = threadIdx.x;

    // ---------- phase 0: init + prep ----------
    if (b == 0) {
        if (t == 0) *dacc = 0.0;
        if (t < NB) cur[t] = 0u;
        if (t < 8) {           // uv: u_i(h)=sum fc1[h][i][o]*attn1[h][o]; v analog
            int hh = t >> 2, r = t & 3, i = r & 1, isv = r >> 1;
            double s = 0.0;
            for (int o = 0; o < 16; ++o)
                s += (double)fc1[hh * 32 + i * 16 + o] * (double)attn1[hh * 32 + isv * 16 + o];
            uv[t] = (float)s;
        }
    }
    grid.sync();

    // ---------- phase 1: scatter (radix partition by bucket, 1 LDS atomic/edge) ----------
    {
        for (int i = t; i < NB; i += SCT) shA[i] = 0u;
        __syncthreads();
        int beg = b * CHUNK;
        unsigned pack[25];                         // d(18b) | rank(14b)<<18
#pragma unroll
        for (int k = 0; k < 25; ++k) {
            int j = k * SCT + t;
            pack[k] = 0xFFFFFFFFu;                 // d-field 0x3FFFF impossible (d<200000)
            if (j < CHUNK) {
                unsigned d = (unsigned)__builtin_nontemporal_load(dst + beg + j);
                unsigned rank = atomicAdd(&shA[d / BNODES], 1u);   // count == rank
                pack[k] = d | (rank << 18);
            }
        }
        __syncthreads();
        for (int i = t; i < NB; i += SCT)
            shB[i] = shA[i] ? atomicAdd(&cur[i], shA[i]) : 0u;
        __syncthreads();
#pragma unroll
        for (int k = 0; k < 25; ++k) {
            if (pack[k] != 0xFFFFFFFFu) {
                int j = k * SCT + t;
                unsigned d = pack[k] & 0x3FFFFu;
                unsigned bb = d / BNODES;
                unsigned dl = d - bb * BNODES;
                unsigned slot = shB[bb] + (pack[k] >> 18);
                if (slot < CAP) {
                    unsigned sn = (unsigned)__builtin_nontemporal_load(src + beg + j);
                    meta[(size_t)bb * CAP + slot] = sn | (dl << 18);
                }
            }
        }
    }
    grid.sync();

    // ---------- phase 2: counting sort meta -> meta2 (1 LDS atomic/edge, no staging) ----------
    {
        size_t boff = (size_t)b * CAP;
        int cnt = min((int)cur[b], CAP);
        for (int i = t; i < BNODES; i += SCT) shA[i] = 0u;
        __syncthreads();
        for (int i = t; i < cnt; i += SCT) {       // pass 1: histogram; rank -> u16 buffer
            unsigned m = meta[boff + i];
            rank16[boff + i] = (unsigned short)atomicAdd(&shA[m >> 18], 1u);
        }
        __syncthreads();
        if (t < BNODES) shC[t] = shA[t];
        __syncthreads();
        for (int d = 1; d < BNODES; d <<= 1) {     // Hillis-Steele inclusive scan
            unsigned v = 0u;
            if (t < BNODES && t >= d) v = shC[t - d];
            __syncthreads();
            if (t < BNODES) shC[t] += v;
            __syncthreads();
        }
        int nb = b * BNODES;
        int nn = min(BNODES, NN - nb);
        if (t < BNODES) {
            unsigned ex = shC[t] - shA[t];         // exclusive base
            shB[t] = ex;
            if (t < nn) {
                nodeoff[nb + t] = (unsigned)boff + ex;
                nodecnt[nb + t] = shA[t];
            }
        }
        __syncthreads();
        for (int i = t; i < cnt; i += SCT) {       // pass 2: place into meta2 (no hazard)
            unsigned m = meta[boff + i];           // L1/L2 hit
            unsigned r = rank16[boff + i];         // same-thread write: program order
            meta2[boff + shB[m >> 18] + r] = m;
        }
    }
    grid.sync();

    // ---------- phase 3: layer-1 + node finalize (thread-per-node, zero atomics) ----------
    {
        int n = b * SCT + t;
        if (n < NN) {
            float u00 = uv[0], u10 = uv[1], v00 = uv[2], v10 = uv[3];
            float u01 = uv[4], u11 = uv[5], v01 = uv[6], v11 = uv[7];
            float2 hd = h[n];
            float c0 = fmaf(hd.x, v00, hd.y * v10);
            float c1 = fmaf(hd.x, v01, hd.y * v11);
            unsigned off = nodeoff[n];
            int cnt = (int)nodecnt[n];
            float s0 = 0.f, s1 = 0.f, s2 = 0.f, s3 = 0.f, s4 = 0.f, s5 = 0.f;
#pragma unroll 4
            for (int k = 0; k < cnt; ++k) {
                unsigned m = meta2[(size_t)off + k];
                float2 hs = h[m & 0x3FFFF];
                float e0 = fmaf(hs.x, u00, fmaf(hs.y, u10, c0));
                float e1 = fmaf(hs.x, u01, fmaf(hs.y, u11, c1));
                e0 = e0 >= 0.f ? e0 : 0.01f * e0;
                e1 = e1 >= 0.f ? e1 : 0.01f * e1;
                float ex0 = __expf(e0);
                float ex1 = __expf(e1);
                s0 += ex0; s1 += ex0 * hs.x; s2 += ex0 * hs.y;
                s3 += ex1; s4 += ex1 * hs.x; s5 += ex1 * hs.y;
            }
            float z0 = 0.f, z1 = 0.f;
#pragma unroll
            for (int o = 0; o < 16; ++o) {      // softmax div + elu + z2 = x @ fc2
                float t0 = s0 > 0.f ? (s1 * fc1[o]      + s2 * fc1[16 + o]) / s0 : 0.f;
                float t1 = s3 > 0.f ? (s4 * fc1[32 + o] + s5 * fc1[48 + o]) / s3 : 0.f;
                float x0 = t0 > 0.f ? t0 : expm1f(t0);
                float x1 = t1 > 0.f ? t1 : expm1f(t1);
                z0 += x0 * fc2[2 * o]     + x1 * fc2[2 * (16 + o)];
                z1 += x0 * fc2[2 * o + 1] + x1 * fc2[2 * (16 + o) + 1];
            }
            z2[n] = make_float2(z0, z1);
        }
    }
    grid.sync();

    // ---------- phase 4: layer-2 + MLP dot (thread-per-node) + f64 reduce ----------
    {
        int n = b * SCT + t;
        double v = 0.0;
        if (n < NN) {
            float a0 = attn2[0], a1 = attn2[1], a2 = attn2[2], a3 = attn2[3];
            float2 zd = z2[n];
            float cd = fmaf(zd.x, a2, zd.y * a3);
            unsigned off = nodeoff[n];
            int cnt = (int)nodecnt[n];
            float s0 = 0.f, s1 = 0.f, s2 = 0.f;
#pragma unroll 4
            for (int k = 0; k < cnt; ++k) {
                unsigned m = meta2[(size_t)off + k];
                float2 zs = z2[m & 0x3FFFF];
                float e = fmaf(zs.x, a0, fmaf(zs.y, a1, cd));
                e = e >= 0.f ? e : 0.01f * e;
                float ex = __expf(e - 48.f);   // const shift cancels; e<=~88, den>=deg*e^-49
                s0 += ex; s1 += ex * zs.x; s2 += ex * zs.y;
            }
            float x0 = s0 > 0.f ? s1 / s0 : 0.f;
            float x1 = s0 > 0.f ? s2 / s0 : 0.f;
            v = (double)x0 * (double)mlp_w[2 * n] + (double)x1 * (double)mlp_w[2 * n + 1];
        }
        for (int off = 32; off > 0; off >>= 1) v += __shfl_down(v, off);
        int lane = t & 63, wid = t >> 6;
        if (lane == 0) sm[wid] = v;
        __syncthreads();
        if (t == 0) {
            double s = 0.0;
#pragma unroll
            for (int w = 0; w < 16; ++w) s += sm[w];
            unsafeAtomicAdd(dacc, s);          // 256 device f64 atomics total
        }
    }
    grid.sync();

    // ---------- phase 5: sigmoid ----------
    if (b == 0 && t == 0) {
        double logit = *dacc + (double)mlp_b[0];
        out[0] = (float)(1.0 / (1.0 + exp(-logit)));
    }
}

extern "C" void kernel_launch(void* const* d_in, const int* in_sizes, int n_in,
                              void* d_out, int out_size, void* d_ws, size_t ws_size,
                              hipStream_t stream) {
    const float2* h    = (const float2*)d_in[0];
    const int*   src   = (const int*)d_in[1];
    const int*   dst   = (const int*)d_in[2];
    const float* fc1   = (const float*)d_in[3];
    const float* attn1 = (const float*)d_in[4];
    const float* fc2   = (const float*)d_in[5];
    const float* attn2 = (const float*)d_in[6];
    const float* mlp_w = (const float*)d_in[7];
    const float* mlp_b = (const float*)d_in[8];
    float* out = (float*)d_out;
    unsigned* ws = (unsigned*)d_ws;

    void* args[] = {(void*)&src, (void*)&dst, (void*)&h, (void*)&fc1, (void*)&attn1,
                    (void*)&fc2, (void*)&attn2, (void*)&mlp_w, (void*)&mlp_b,
                    (void*)&out, (void*)&ws};
    hipLaunchCooperativeKernel((void*)k_fused, dim3(NB), dim3(SCT), args, 0, stream);
}

// Round 18
// 255.742 us; speedup vs baseline: 1.4838x; 1.4838x over previous
//
#include <hip/hip_runtime.h>
#include <hip/hip_bf16.h>
#include <math.h>

#define NN 200000
#define NE 6400000

#define BNODES 782                     // nodes per bucket (NB = 256 = #CUs)
#define NB 256
#define CAP 27648                      // 27*1024; mean 25000 -> +16 sigma
#define NBLK_SC 256
#define SCT 1024                       // scatter/sort block threads (16 waves)
#define CHUNK (NE / NBLK_SC)           // 25000; 25 iters/thread
#define SREG 27                        // sort: CAP/SCT register records/thread

// ---- workspace layout (4-byte words) ----
#define W_DACC 0                       // double (2 words)
#define W_DONE 2                       // 1 uint: gat2 completion counter
#define W_UV   4                       // 8 floats
#define W_CUR  16                      // NB uints
#define W_NOFF 1024                    // NN uints
#define W_NCNT (W_NOFF + NN)           // NN uints
#define W_META (W_NCNT + NN)           // NB*CAP u32: sn(18b) | dl(10b)<<18
#define W_Z2   (W_META + NB*CAP)       // 2*NN f32
#define W_TOTAL (W_Z2 + 2*NN)          // ~7.9M words = 31.5 MB

// init + prep merged: zero dacc/done/cur, compute uv from fc1/attn1
__global__ void k_init(unsigned* __restrict__ ws, const float* __restrict__ fc1,
                       const float* __restrict__ attn1) {
    int t = threadIdx.x;
    if (t == 0) { *(double*)ws = 0.0; ws[W_DONE] = 0u; }
    if (t < NB) ws[W_CUR + t] = 0u;
    if (t >= 256 && t < 264) {
        int q = t - 256;
        int hh = q >> 2, r = q & 3, i = r & 1, isv = r >> 1;
        double s = 0.0;
        for (int o = 0; o < 16; ++o)
            s += (double)fc1[hh * 32 + i * 16 + o] * (double)attn1[hh * 32 + isv * 16 + o];
        ((float*)(ws + W_UV))[q] = (float)s;
    }
}

// radix partition by dst bucket (b = d/782), 4B meta records, ONE LDS atomic/edge.
__launch_bounds__(SCT)
__global__ void k_scatter(const int* __restrict__ src, const int* __restrict__ dst,
                          unsigned* __restrict__ meta, unsigned* __restrict__ cur) {
    __shared__ unsigned cnt[NB], gbase[NB];           // 2 KB
    for (int i = threadIdx.x; i < NB; i += SCT) cnt[i] = 0u;
    __syncthreads();
    int beg = blockIdx.x * CHUNK;
    unsigned pack[25];                                // d(18b) | rank(14b)<<18
#pragma unroll
    for (int k = 0; k < 25; ++k) {
        int j = k * SCT + threadIdx.x;
        pack[k] = 0xFFFFFFFFu;                        // d-field 0x3FFFF impossible (d<200000)
        if (j < CHUNK) {
            unsigned d = (unsigned)__builtin_nontemporal_load(dst + beg + j);
            unsigned rank = atomicAdd(&cnt[d / BNODES], 1u);   // count == rank
            pack[k] = d | (rank << 18);
        }
    }
    __syncthreads();
    for (int i = threadIdx.x; i < NB; i += SCT)
        gbase[i] = cnt[i] ? atomicAdd(&cur[i], cnt[i]) : 0u;
    __syncthreads();
#pragma unroll
    for (int k = 0; k < 25; ++k) {
        if (pack[k] != 0xFFFFFFFFu) {
            int j = k * SCT + threadIdx.x;
            unsigned d = pack[k] & 0x3FFFFu;
            unsigned b = d / BNODES;
            unsigned dl = d - b * BNODES;
            unsigned slot = gbase[b] + (pack[k] >> 18);
            if (slot < CAP) {
                unsigned sn = (unsigned)__builtin_nontemporal_load(src + beg + j);
                meta[(size_t)b * CAP + slot] = sn | (dl << 18);
            }
        }
    }
}

// in-place counting sort by node within each bucket; 256 blocks (1/CU, balanced);
// records staged in registers (27/thread, static); ONE LDS atomic/edge.
__launch_bounds__(SCT)
__global__ void k_sort(unsigned* __restrict__ meta, const unsigned* __restrict__ cur,
                       unsigned* __restrict__ nodeoff, unsigned* __restrict__ nodecnt) {
    __shared__ unsigned hist[BNODES], base[BNODES], scan[BNODES];   // 9.4 KB
    int b = blockIdx.x, t = threadIdx.x;
    size_t boff = (size_t)b * CAP;
    int cnt = min((int)cur[b], CAP);
    for (int i = t; i < BNODES; i += SCT) hist[i] = 0u;
    __syncthreads();
    unsigned rm[SREG], rr[SREG];
#pragma unroll
    for (int k = 0; k < SREG; ++k) {
        int i = k * SCT + t;
        rm[k] = 0xFFFFFFFFu;
        rr[k] = 0u;
        if (i < cnt) {
            rm[k] = meta[boff + i];
            rr[k] = atomicAdd(&hist[rm[k] >> 18], 1u);    // rank within node
        }
    }
    asm volatile("s_waitcnt vmcnt(0)" ::: "memory");      // all reads before any write
    __syncthreads();
    if (t < BNODES) scan[t] = hist[t];
    __syncthreads();
    for (int d = 1; d < BNODES; d <<= 1) {                // Hillis-Steele inclusive scan
        unsigned v = 0u;
        if (t < BNODES && t >= d) v = scan[t - d];
        __syncthreads();
        if (t < BNODES) scan[t] += v;
        __syncthreads();
    }
    int nb = b * BNODES;
    int nn = min(BNODES, NN - nb);
    if (t < BNODES) {
        unsigned ex = scan[t] - hist[t];                  // exclusive base
        base[t] = ex;
        if (t < nn) {
            nodeoff[nb + t] = (unsigned)boff + ex;
            nodecnt[nb + t] = hist[t];
        }
    }
    __syncthreads();
#pragma unroll
    for (int k = 0; k < SREG; ++k)
        if (rm[k] != 0xFFFFFFFFu)
            meta[boff + base[rm[k] >> 18] + rr[k]] = rm[k];
}

// layer-1 + node finalize fused: thread-per-node, zero atomics; h gathers L2-hit.
__global__ void k_gat1(const unsigned* __restrict__ meta, const unsigned* __restrict__ nodeoff,
                       const unsigned* __restrict__ nodecnt, const float2* __restrict__ h,
                       const float* __restrict__ uv, const float* __restrict__ fc1,
                       const float* __restrict__ fc2, float2* __restrict__ z2) {
    int n = blockIdx.x * blockDim.x + threadIdx.x;
    if (n >= NN) return;
    float u00 = uv[0], u10 = uv[1], v00 = uv[2], v10 = uv[3];
    float u01 = uv[4], u11 = uv[5], v01 = uv[6], v11 = uv[7];
    float2 hd = h[n];
    float c0 = fmaf(hd.x, v00, hd.y * v10);
    float c1 = fmaf(hd.x, v01, hd.y * v11);
    unsigned off = nodeoff[n];
    int cnt = (int)nodecnt[n];
    float s0 = 0.f, s1 = 0.f, s2 = 0.f, s3 = 0.f, s4 = 0.f, s5 = 0.f;
#pragma unroll 4
    for (int k = 0; k < cnt; ++k) {
        unsigned m = meta[(size_t)off + k];
        float2 hs = h[m & 0x3FFFF];
        float e0 = fmaf(hs.x, u00, fmaf(hs.y, u10, c0));
        float e1 = fmaf(hs.x, u01, fmaf(hs.y, u11, c1));
        e0 = e0 >= 0.f ? e0 : 0.01f * e0;
        e1 = e1 >= 0.f ? e1 : 0.01f * e1;
        float ex0 = __expf(e0);
        float ex1 = __expf(e1);
        s0 += ex0; s1 += ex0 * hs.x; s2 += ex0 * hs.y;
        s3 += ex1; s4 += ex1 * hs.x; s5 += ex1 * hs.y;
    }
    float z0 = 0.f, z1 = 0.f;
#pragma unroll
    for (int o = 0; o < 16; ++o) {      // softmax div + elu + z2 = x @ fc2
        float t0 = s0 > 0.f ? (s1 * fc1[o]      + s2 * fc1[16 + o]) / s0 : 0.f;
        float t1 = s3 > 0.f ? (s4 * fc1[32 + o] + s5 * fc1[48 + o]) / s3 : 0.f;
        float x0 = t0 > 0.f ? t0 : expm1f(t0);
        float x1 = t1 > 0.f ? t1 : expm1f(t1);
        z0 += x0 * fc2[2 * o]     + x1 * fc2[2 * (16 + o)];
        z1 += x0 * fc2[2 * o + 1] + x1 * fc2[2 * (16 + o) + 1];
    }
    z2[n] = make_float2(z0, z1);
}

// layer-2 + MLP dot + f64 block reduce; LAST block computes the sigmoid (no k_out).
__global__ void k_gat2(const unsigned* __restrict__ meta, const unsigned* __restrict__ nodeoff,
                       const unsigned* __restrict__ nodecnt, const float2* __restrict__ z2,
                       const float* __restrict__ attn2, const float* __restrict__ mlp_w,
                       const float* __restrict__ mlp_b, double* __restrict__ dacc,
                       unsigned* __restrict__ done, float* __restrict__ out) {
    int n = blockIdx.x * blockDim.x + threadIdx.x;
    double v = 0.0;
    if (n < NN) {
        float a0 = attn2[0], a1 = attn2[1], a2 = attn2[2], a3 = attn2[3];
        float2 zd = z2[n];
        float cd = fmaf(zd.x, a2, zd.y * a3);
        unsigned off = nodeoff[n];
        int cnt = (int)nodecnt[n];
        float s0 = 0.f, s1 = 0.f, s2 = 0.f;
#pragma unroll 4
        for (int k = 0; k < cnt; ++k) {
            unsigned m = meta[(size_t)off + k];
            float2 zs = z2[m & 0x3FFFF];
            float e = fmaf(zs.x, a0, fmaf(zs.y, a1, cd));
            e = e >= 0.f ? e : 0.01f * e;
            float ex = __expf(e - 48.f);   // const shift cancels; e<=~88, den>=deg*e^-49
            s0 += ex; s1 += ex * zs.x; s2 += ex * zs.y;
        }
        float x0 = s0 > 0.f ? s1 / s0 : 0.f;
        float x1 = s0 > 0.f ? s2 / s0 : 0.f;
        v = (double)x0 * (double)mlp_w[2 * n] + (double)x1 * (double)mlp_w[2 * n + 1];
    }
    for (int off = 32; off > 0; off >>= 1) v += __shfl_down(v, off);
    __shared__ double sm[4];
    int lane = threadIdx.x & 63, wid = threadIdx.x >> 6;
    if (lane == 0) sm[wid] = v;
    __syncthreads();
    if (threadIdx.x == 0) {
        double sum = sm[0] + sm[1] + sm[2] + sm[3];
        unsafeAtomicAdd(dacc, sum);                  // device-scope, memory-side
        __threadfence();                             // dacc-add visible before counter
        unsigned prev = atomicAdd(done, 1u);         // device-scope counter
        if (prev == gridDim.x - 1) {                 // last block: all sums landed
            __threadfence();
            double logit = __hip_atomic_load(dacc, __ATOMIC_RELAXED,
                                             __HIP_MEMORY_SCOPE_AGENT) +
                           (double)mlp_b[0];
            out[0] = (float)(1.0 / (1.0 + exp(-logit)));
        }
    }
}

extern "C" void kernel_launch(void* const* d_in, const int* in_sizes, int n_in,
                              void* d_out, int out_size, void* d_ws, size_t ws_size,
                              hipStream_t stream) {
    const float2* h    = (const float2*)d_in[0];
    const int*   src   = (const int*)d_in[1];
    const int*   dst   = (const int*)d_in[2];
    const float* fc1   = (const float*)d_in[3];
    const float* attn1 = (const float*)d_in[4];
    const float* fc2   = (const float*)d_in[5];
    const float* attn2 = (const float*)d_in[6];
    const float* mlp_w = (const float*)d_in[7];
    const float* mlp_b = (const float*)d_in[8];
    float* out = (float*)d_out;

    unsigned* ws      = (unsigned*)d_ws;
    double*   dacc    = (double*)d_ws;
    unsigned* done    = ws + W_DONE;
    float*    uv      = (float*)(ws + W_UV);
    unsigned* cur     = ws + W_CUR;
    unsigned* nodeoff = ws + W_NOFF;
    unsigned* nodecnt = ws + W_NCNT;
    unsigned* meta    = ws + W_META;
    float2*   z2      = (float2*)(ws + W_Z2);

    const int NG = (NN + 255) / 256;            // 782

    hipLaunchKernelGGL(k_init, dim3(1), dim3(264), 0, stream, ws, fc1, attn1);
    hipLaunchKernelGGL(k_scatter, dim3(NBLK_SC), dim3(SCT), 0, stream,
                       src, dst, meta, cur);
    hipLaunchKernelGGL(k_sort, dim3(NB), dim3(SCT), 0, stream,
                       meta, cur, nodeoff, nodecnt);
    hipLaunchKernelGGL(k_gat1, dim3(NG), dim3(256), 0, stream,
                       meta, nodeoff, nodecnt, (const float2*)h, uv, fc1, fc2, z2);
    hipLaunchKernelGGL(k_gat2, dim3(NG), dim3(256), 0, stream,
                       meta, nodeoff, nodecnt, (const float2*)z2, attn2, mlp_w,
                       mlp_b, dacc, done, out);
}